// Round 1
// baseline (1987.671 us; speedup 1.0000x reference)
//
#include <hip/hip_runtime.h>
#include <cstddef>
#include <cstdint>

#define B_ 4
#define N_ 16384
#define M_ 2048
#define C_ 128
#define NQ (B_*M_)         // 8192 queries
#define NSAMP 32
#define SAMP (NQ*NSAMP)    // 262144 samples
#define EPS_ 1e-5f
#define R2_ 9.0f

typedef short s8v  __attribute__((ext_vector_type(8)));
typedef short s4v  __attribute__((ext_vector_type(4)));
typedef float f32x4 __attribute__((ext_vector_type(4)));

// stats layout (floats) in ws: shift0 sum[64]@0, sq[64]@64; shift1 sum[3]@128, sq[3]@136;
// bn1 sum[128]@144, sq[128]@272; bn2 sum[256]@400, sq[256]@656. total < 1024.
#define ST_S0S 0
#define ST_S0Q 64
#define ST_S1S 128
#define ST_S1Q 136
#define ST_M1S 144
#define ST_M1Q 272
#define ST_M2S 400
#define ST_M2Q 656

__device__ __forceinline__ unsigned short f2bf(float f) {
    unsigned int u = __builtin_bit_cast(unsigned int, f);
    u += 0x7fffu + ((u >> 16) & 1u);     // round-to-nearest-even
    return (unsigned short)(u >> 16);
}
__device__ __forceinline__ float bf2f(unsigned short h) {
    unsigned int u = ((unsigned int)h) << 16;
    return __builtin_bit_cast(float, u);
}

// ---- prep: reorder+pad mlp_w0 (128x131 -> 128x160 bf16, feat-first), cast mlp_w1 (256x128 bf16)
__global__ void k_prep_w(const float* __restrict__ w0, const float* __restrict__ w1,
                         unsigned short* __restrict__ w0p, unsigned short* __restrict__ w1p) {
    int i = blockIdx.x * 256 + threadIdx.x;
    const int tot0 = 128 * 160;
    if (i < tot0) {
        int o = i / 160, c = i - o * 160;
        float v = 0.f;
        if (c < 128)      v = w0[o * 131 + 3 + c];      // feat channels (orig 3..130)
        else if (c < 131) v = w0[o * 131 + (c - 128)];  // rel xyz (orig 0..2)
        w0p[i] = f2bf(v);
    }
    int j = i - tot0;
    if (j >= 0 && j < 256 * 128) w1p[j] = f2bf(w1[j]);
}

// ---- transpose backbone_features (B,C,N) f32 -> featT (B,N,C) bf16
__global__ void k_transpose(const float* __restrict__ feat, unsigned short* __restrict__ featT) {
    __shared__ unsigned short tl[64][130];   // stride 130 (65 dwords, odd -> conflict-free)
    int b  = blockIdx.x >> 8;
    int n0 = (blockIdx.x & 255) * 64;
    const float* src = feat + (size_t)b * C_ * N_;
    int t = threadIdx.x;
    for (int i = 0; i < 32; ++i) {
        int lin = i * 256 + t;
        int c = lin >> 6, n = lin & 63;
        tl[n][c] = f2bf(src[(size_t)c * N_ + n0 + n]);
    }
    __syncthreads();
    unsigned short* dst = featT + ((size_t)b * N_ + n0) * 128;
    for (int i = 0; i < 32; ++i) {
        int lin = i * 256 + t;
        int n = lin >> 7, c = lin & 127;
        dst[(size_t)n * 128 + c] = tl[n][c];
    }
}

// ---- shift MLP layer 0: t0 = w0s @ q  (per point), + channel sum/sumsq
__global__ void k_shift0(const float* __restrict__ xyz, const float* __restrict__ w0s,
                         float* __restrict__ t0, float* __restrict__ stats) {
    __shared__ float ls[64], lq[64];
    int t = threadIdx.x;
    if (t < 64) { ls[t] = 0.f; lq[t] = 0.f; }
    __syncthreads();
    int p = blockIdx.x * 256 + t;
    float q0 = xyz[p*3], q1 = xyz[p*3+1], q2 = xyz[p*3+2];
    for (int o = 0; o < 64; ++o) {
        float v = w0s[o*3]*q0 + w0s[o*3+1]*q1 + w0s[o*3+2]*q2;
        t0[p*64+o] = v;
        atomicAdd(&ls[o], v);
        atomicAdd(&lq[o], v*v);
    }
    __syncthreads();
    if (t < 64) { atomicAdd(&stats[ST_S0S + t], ls[t]); atomicAdd(&stats[ST_S0Q + t], lq[t]); }
}

// ---- shift layer 1: h0 = relu(bn(t0)); t1 = w1s @ h0; + channel sums
__global__ void k_shift1(const float* __restrict__ t0, const float* __restrict__ w1s,
                         const float* __restrict__ g0, const float* __restrict__ b0,
                         float* __restrict__ t1, float* __restrict__ stats) {
    __shared__ float aa[64], bb[64], ls[3], lq[3];
    int t = threadIdx.x;
    if (t < 64) {
        float mean = stats[ST_S0S + t] * (1.f / NQ);
        float var  = stats[ST_S0Q + t] * (1.f / NQ) - mean * mean;
        float a = g0[t] * rsqrtf(var + EPS_);
        aa[t] = a; bb[t] = b0[t] - mean * a;
    }
    if (t < 3) { ls[t] = 0.f; lq[t] = 0.f; }
    __syncthreads();
    int p = blockIdx.x * 256 + t;
    float h[64];
    for (int c = 0; c < 64; ++c) h[c] = fmaxf(0.f, aa[c] * t0[p*64+c] + bb[c]);
    for (int o = 0; o < 3; ++o) {
        float v = 0.f;
        for (int c = 0; c < 64; ++c) v += w1s[o*64+c] * h[c];
        t1[p*3+o] = v;
        atomicAdd(&ls[o], v);
        atomicAdd(&lq[o], v*v);
    }
    __syncthreads();
    if (t < 3) { atomicAdd(&stats[ST_S1S + t], ls[t]); atomicAdd(&stats[ST_S1Q + t], lq[t]); }
}

// ---- shift output: new_xyz = relu(bn(t1))
__global__ void k_shift2(const float* __restrict__ t1, const float* __restrict__ g1,
                         const float* __restrict__ b1, const float* __restrict__ stats,
                         float* __restrict__ nxyz) {
    int p = blockIdx.x * 256 + threadIdx.x;
    for (int o = 0; o < 3; ++o) {
        float mean = stats[ST_S1S + o] * (1.f / NQ);
        float var  = stats[ST_S1Q + o] * (1.f / NQ) - mean * mean;
        float a = g1[o] * rsqrtf(var + EPS_);
        float bbv = b1[o] - mean * a;
        nxyz[p*3+o] = fmaxf(0.f, a * t1[p*3+o] + bbv);
    }
}

// ---- ball query: first 32 indices with d2 < 9, ascending scan, pad with first (0 if none)
__global__ void k_ballq(const float* __restrict__ bxyz, const float* __restrict__ nxyz,
                        int* __restrict__ idxb) {
    int p = blockIdx.x * 256 + threadIdx.x;
    int b = p >> 11;                         // p / M_
    float qx = nxyz[p*3], qy = nxyz[p*3+1], qz = nxyz[p*3+2];
    float sq = __fadd_rn(__fadd_rn(__fmul_rn(qx,qx), __fmul_rn(qy,qy)), __fmul_rn(qz,qz));
    const float* bp = bxyz + (size_t)b * N_ * 3;
    int cnt = 0, first = 0;
    for (int j = 0; j < N_; ++j) {
        float x = bp[j*3], y = bp[j*3+1], z = bp[j*3+2];
        float sx  = __fadd_rn(__fadd_rn(__fmul_rn(x,x), __fmul_rn(y,y)), __fmul_rn(z,z));
        float dot = __fadd_rn(__fadd_rn(__fmul_rn(qx,x), __fmul_rn(qy,y)), __fmul_rn(qz,z));
        float d2  = __fsub_rn(__fadd_rn(sq, sx), __fmul_rn(2.0f, dot));
        if (d2 < R2_) {
            if (cnt == 0) first = j;
            idxb[p*32 + cnt] = j;
            if (++cnt == 32) break;
        }
    }
    for (int k = cnt; k < 32; ++k) idxb[p*32 + k] = first;
}

// ---- GEMM1: gather g (160ch padded) per query, y1 = w0p @ g (bf16 MFMA), store y1 bf16, fused stats
__global__ void __launch_bounds__(256)
k_gemm1(const unsigned short* __restrict__ featT, const float* __restrict__ bxyz,
        const float* __restrict__ nxyz, const int* __restrict__ idxb,
        const unsigned short* __restrict__ w0p, unsigned short* __restrict__ y1,
        float* __restrict__ stats) {
    __shared__ unsigned short gt[32][168];   // [sample][channel], stride 168 -> <=2-way conflicts
    __shared__ int pidx[32];
    int tid  = threadIdx.x;
    int wave = tid >> 6, lane = tid & 63, quad = lane >> 4, l16 = lane & 15;

    s8v afr[2][5];                            // A fragments: rows wave*32 + t2*16 + l16
    for (int t2 = 0; t2 < 2; ++t2)
        for (int kk = 0; kk < 5; ++kk) {
            int row = wave*32 + t2*16 + l16;
            afr[t2][kk] = *(const s8v*)(w0p + row*160 + kk*32 + quad*8);
        }
    f32x4 ssum[2] = {}; f32x4 ssq[2] = {};

    for (int qi = 0; qi < 8; ++qi) {
        int gq = blockIdx.x * 8 + qi;
        int b  = gq >> 11;
        if (tid < 32) pidx[tid] = idxb[gq*32 + tid];
        __syncthreads();
        // stage features: 8 threads per sample, 16 ch each (two 16B loads)
        {
            int s = tid >> 3, part = tid & 7;
            int pp = pidx[s];
            const unsigned short* src = featT + ((size_t)(b * N_ + pp)) * 128 + part * 16;
            s8v v0 = *(const s8v*)src;
            s8v v1 = *(const s8v*)(src + 8);
            *(s8v*)&gt[s][part*16]     = v0;
            *(s8v*)&gt[s][part*16 + 8] = v1;
        }
        if (tid < 32) {   // rel xyz at ch 128..130, zeros 131..159
            int pp = pidx[tid];
            const float* bx = bxyz + (size_t)(b * N_ + pp) * 3;
            float rx = bx[0] - nxyz[gq*3];
            float ry = bx[1] - nxyz[gq*3+1];
            float rz = bx[2] - nxyz[gq*3+2];
            gt[tid][128] = f2bf(rx); gt[tid][129] = f2bf(ry); gt[tid][130] = f2bf(rz);
            for (int c = 131; c < 160; ++c) gt[tid][c] = 0;
        }
        __syncthreads();
        f32x4 acc[2][2] = {};
        for (int kk = 0; kk < 5; ++kk) {
            s8v bf0 = *(const s8v*)&gt[l16][kk*32 + quad*8];
            s8v bf1 = *(const s8v*)&gt[l16 + 16][kk*32 + quad*8];
            for (int t2 = 0; t2 < 2; ++t2) {
                acc[t2][0] = __builtin_amdgcn_mfma_f32_16x16x32_bf16(afr[t2][kk], bf0, acc[t2][0], 0, 0, 0);
                acc[t2][1] = __builtin_amdgcn_mfma_f32_16x16x32_bf16(afr[t2][kk], bf1, acc[t2][1], 0, 0, 0);
            }
        }
        for (int t2 = 0; t2 < 2; ++t2)
            for (int n = 0; n < 2; ++n) {
                int sg  = gq*32 + n*16 + l16;
                int ch0 = wave*32 + t2*16 + quad*4;
                f32x4 a = acc[t2][n];
                s4v pk;
                pk.x = (short)f2bf(a.x); pk.y = (short)f2bf(a.y);
                pk.z = (short)f2bf(a.z); pk.w = (short)f2bf(a.w);
                *(s4v*)(y1 + (size_t)sg * 128 + ch0) = pk;
                ssum[t2] += a;
                ssq[t2]  += a * a;
            }
        __syncthreads();
    }
    for (int t2 = 0; t2 < 2; ++t2)
        for (int r = 0; r < 4; ++r) {
            float s = ssum[t2][r], q = ssq[t2][r];
            for (int mk = 1; mk < 16; mk <<= 1) { s += __shfl_xor(s, mk); q += __shfl_xor(q, mk); }
            if (l16 == 0) {
                int ch = wave*32 + t2*16 + quad*4 + r;
                atomicAdd(&stats[ST_M1S + ch], s);
                atomicAdd(&stats[ST_M1Q + ch], q);
            }
        }
}

// ---- GEMM2: h1 = relu(bn1(y1)) staged bf16; y2 = w1p @ h1.
// FINAL=false: accumulate bn2 stats only.  FINAL=true: bn2+relu+max-over-32 -> out.
template <bool FINAL>
__global__ void __launch_bounds__(256)
k_gemm2(const unsigned short* __restrict__ y1, const unsigned short* __restrict__ w1p,
        const float* __restrict__ g1m, const float* __restrict__ b1m,
        const float* __restrict__ g2m, const float* __restrict__ b2m,
        float* __restrict__ stats, float* __restrict__ out) {
    __shared__ unsigned short ht[32][136];    // stride 136 -> <=2-way conflicts
    __shared__ float a1l[128], b1l[128];
    __shared__ float a2l[256], b2l[256];
    int tid = threadIdx.x;
    if (tid < 128) {
        float mean = stats[ST_M1S + tid] * (1.f / SAMP);
        float var  = stats[ST_M1Q + tid] * (1.f / SAMP) - mean * mean;
        float a = g1m[tid] * rsqrtf(var + EPS_);
        a1l[tid] = a; b1l[tid] = b1m[tid] - mean * a;
    }
    if (FINAL) {
        float mean = stats[ST_M2S + tid] * (1.f / SAMP);
        float var  = stats[ST_M2Q + tid] * (1.f / SAMP) - mean * mean;
        float a = g2m[tid] * rsqrtf(var + EPS_);
        a2l[tid] = a; b2l[tid] = b2m[tid] - mean * a;
    }
    __syncthreads();
    int wave = tid >> 6, lane = tid & 63, quad = lane >> 4, l16 = lane & 15;
    s8v afr[4][4];
    for (int t4 = 0; t4 < 4; ++t4)
        for (int kk = 0; kk < 4; ++kk) {
            int row = wave*64 + t4*16 + l16;
            afr[t4][kk] = *(const s8v*)(w1p + row*128 + kk*32 + quad*8);
        }
    f32x4 ssum[4] = {}; f32x4 ssq[4] = {};
    for (int qi = 0; qi < 8; ++qi) {
        int gq = blockIdx.x * 8 + qi;
        {   // stage h1 = relu(bn1(y1)) as bf16
            int s = tid >> 3, part = tid & 7;
            const unsigned short* src = y1 + ((size_t)(gq*32 + s)) * 128 + part * 16;
            s8v v0 = *(const s8v*)src;
            s8v v1 = *(const s8v*)(src + 8);
            s8v o0, o1;
            for (int e = 0; e < 8; ++e) {
                int c0 = part*16 + e, c1 = c0 + 8;
                float f0 = bf2f((unsigned short)v0[e]);
                float f1 = bf2f((unsigned short)v1[e]);
                o0[e] = (short)f2bf(fmaxf(0.f, a1l[c0]*f0 + b1l[c0]));
                o1[e] = (short)f2bf(fmaxf(0.f, a1l[c1]*f1 + b1l[c1]));
            }
            *(s8v*)&ht[s][part*16]     = o0;
            *(s8v*)&ht[s][part*16 + 8] = o1;
        }
        __syncthreads();
        f32x4 acc[4][2] = {};
        for (int kk = 0; kk < 4; ++kk) {
            s8v bf0 = *(const s8v*)&ht[l16][kk*32 + quad*8];
            s8v bf1 = *(const s8v*)&ht[l16 + 16][kk*32 + quad*8];
            for (int t4 = 0; t4 < 4; ++t4) {
                acc[t4][0] = __builtin_amdgcn_mfma_f32_16x16x32_bf16(afr[t4][kk], bf0, acc[t4][0], 0, 0, 0);
                acc[t4][1] = __builtin_amdgcn_mfma_f32_16x16x32_bf16(afr[t4][kk], bf1, acc[t4][1], 0, 0, 0);
            }
        }
        if (FINAL) {
            for (int t4 = 0; t4 < 4; ++t4) {
                int ch0 = wave*64 + t4*16 + quad*4;
                f32x4 res;
                for (int r = 0; r < 4; ++r) {
                    float a2 = a2l[ch0 + r], bb2 = b2l[ch0 + r];
                    float v0 = fmaxf(0.f, a2 * acc[t4][0][r] + bb2);
                    float v1 = fmaxf(0.f, a2 * acc[t4][1][r] + bb2);
                    float m = fmaxf(v0, v1);
                    for (int mk = 1; mk < 16; mk <<= 1) m = fmaxf(m, __shfl_xor(m, mk));
                    res[r] = m;
                }
                if (l16 == 0) *(f32x4*)(out + (size_t)gq * 256 + ch0) = res;
            }
        } else {
            for (int t4 = 0; t4 < 4; ++t4)
                for (int n = 0; n < 2; ++n) { ssum[t4] += acc[t4][n]; ssq[t4] += acc[t4][n] * acc[t4][n]; }
        }
        __syncthreads();
    }
    if (!FINAL) {
        for (int t4 = 0; t4 < 4; ++t4)
            for (int r = 0; r < 4; ++r) {
                float s = ssum[t4][r], q = ssq[t4][r];
                for (int mk = 1; mk < 16; mk <<= 1) { s += __shfl_xor(s, mk); q += __shfl_xor(q, mk); }
                if (l16 == 0) {
                    int ch = wave*64 + t4*16 + quad*4 + r;
                    atomicAdd(&stats[ST_M2S + ch], s);
                    atomicAdd(&stats[ST_M2Q + ch], q);
                }
            }
    }
}

extern "C" void kernel_launch(void* const* d_in, const int* in_sizes, int n_in,
                              void* d_out, int out_size, void* d_ws, size_t ws_size,
                              hipStream_t stream) {
    const float* ffps = (const float*)d_in[0];
    const float* bxyz = (const float*)d_in[1];
    const float* feat = (const float*)d_in[2];
    const float* sw0  = (const float*)d_in[3];
    const float* sg0  = (const float*)d_in[4];
    const float* sb0  = (const float*)d_in[5];
    const float* sw1  = (const float*)d_in[6];
    const float* sg1  = (const float*)d_in[7];
    const float* sb1  = (const float*)d_in[8];
    const float* mw0  = (const float*)d_in[9];
    const float* mg0  = (const float*)d_in[10];
    const float* mb0  = (const float*)d_in[11];
    const float* mw1  = (const float*)d_in[12];
    const float* mg1  = (const float*)d_in[13];
    const float* mb1  = (const float*)d_in[14];
    float* out = (float*)d_out;

    char* ws = (char*)d_ws;
    size_t off = 0;
    auto alloc = [&](size_t bytes) -> void* {
        void* p = ws + off;
        off += (bytes + 255) & ~(size_t)255;
        return p;
    };
    float*          stats = (float*)alloc(1024 * 4);
    float*          t0    = (float*)alloc((size_t)NQ * 64 * 4);
    float*          t1    = (float*)alloc((size_t)NQ * 3 * 4);
    float*          nxyz  = (float*)alloc((size_t)NQ * 3 * 4);
    int*            idxb  = (int*)alloc((size_t)NQ * 32 * 4);
    unsigned short* w0p   = (unsigned short*)alloc(128 * 160 * 2);
    unsigned short* w1p   = (unsigned short*)alloc(256 * 128 * 2);
    unsigned short* featT = (unsigned short*)alloc((size_t)B_ * N_ * 128 * 2);
    unsigned short* y1    = (unsigned short*)alloc((size_t)SAMP * 128 * 2);
    (void)in_sizes; (void)n_in; (void)out_size; (void)ws_size;

    hipMemsetAsync(stats, 0, 1024 * 4, stream);
    k_prep_w   <<<208, 256, 0, stream>>>(mw0, mw1, w0p, w1p);
    k_transpose<<<B_ * 256, 256, 0, stream>>>(feat, featT);
    k_shift0   <<<NQ / 256, 256, 0, stream>>>(ffps, sw0, t0, stats);
    k_shift1   <<<NQ / 256, 256, 0, stream>>>(t0, sw1, sg0, sb0, t1, stats);
    k_shift2   <<<NQ / 256, 256, 0, stream>>>(t1, sg1, sb1, stats, nxyz);
    k_ballq    <<<NQ / 256, 256, 0, stream>>>(bxyz, nxyz, idxb);
    k_gemm1    <<<NQ / 8, 256, 0, stream>>>(featT, bxyz, nxyz, idxb, w0p, y1, stats);
    k_gemm2<false><<<NQ / 8, 256, 0, stream>>>(y1, w1p, mg0, mb0, mg1, mb1, stats, out);
    k_gemm2<true> <<<NQ / 8, 256, 0, stream>>>(y1, w1p, mg0, mb0, mg1, mb1, stats, out);
}

// Round 2
// 720.596 us; speedup vs baseline: 2.7584x; 2.7584x over previous
//
#include <hip/hip_runtime.h>
#include <cstddef>
#include <cstdint>

#define B_ 4
#define N_ 16384
#define M_ 2048
#define C_ 128
#define NQ (B_*M_)         // 8192 queries
#define NSAMP 32
#define SAMP (NQ*NSAMP)    // 262144 samples
#define EPS_ 1e-5f
#define R2_ 9.0f

typedef short s8v  __attribute__((ext_vector_type(8)));
typedef short s4v  __attribute__((ext_vector_type(4)));
typedef float f32x4 __attribute__((ext_vector_type(4)));

// stats layout (floats) in ws: shift0 sum[64]@0, sq[64]@64; shift1 sum[3]@128, sq[3]@136;
// bn1 sum[128]@144, sq[128]@272; bn2 sum[256]@400, sq[256]@656. total < 1024.
#define ST_S0S 0
#define ST_S0Q 64
#define ST_S1S 128
#define ST_S1Q 136
#define ST_M1S 144
#define ST_M1Q 272
#define ST_M2S 400
#define ST_M2Q 656

__device__ __forceinline__ unsigned short f2bf(float f) {
    unsigned int u = __builtin_bit_cast(unsigned int, f);
    u += 0x7fffu + ((u >> 16) & 1u);     // round-to-nearest-even
    return (unsigned short)(u >> 16);
}
__device__ __forceinline__ float bf2f(unsigned short h) {
    unsigned int u = ((unsigned int)h) << 16;
    return __builtin_bit_cast(float, u);
}

// ---- prep: reorder+pad mlp_w0 (128x131 -> 128x160 bf16, feat-first), cast mlp_w1 (256x128 bf16)
__global__ void k_prep_w(const float* __restrict__ w0, const float* __restrict__ w1,
                         unsigned short* __restrict__ w0p, unsigned short* __restrict__ w1p) {
    int i = blockIdx.x * 256 + threadIdx.x;
    const int tot0 = 128 * 160;
    if (i < tot0) {
        int o = i / 160, c = i - o * 160;
        float v = 0.f;
        if (c < 128)      v = w0[o * 131 + 3 + c];      // feat channels (orig 3..130)
        else if (c < 131) v = w0[o * 131 + (c - 128)];  // rel xyz (orig 0..2)
        w0p[i] = f2bf(v);
    }
    int j = i - tot0;
    if (j >= 0 && j < 256 * 128) w1p[j] = f2bf(w1[j]);
}

// ---- transpose backbone_features (B,C,N) f32 -> featT (B,N,C) bf16
__global__ void k_transpose(const float* __restrict__ feat, unsigned short* __restrict__ featT) {
    __shared__ unsigned short tl[64][130];   // stride 130 (65 dwords, odd -> conflict-free)
    int b  = blockIdx.x >> 8;
    int n0 = (blockIdx.x & 255) * 64;
    const float* src = feat + (size_t)b * C_ * N_;
    int t = threadIdx.x;
    for (int i = 0; i < 32; ++i) {
        int lin = i * 256 + t;
        int c = lin >> 6, n = lin & 63;
        tl[n][c] = f2bf(src[(size_t)c * N_ + n0 + n]);
    }
    __syncthreads();
    unsigned short* dst = featT + ((size_t)b * N_ + n0) * 128;
    for (int i = 0; i < 32; ++i) {
        int lin = i * 256 + t;
        int n = lin >> 7, c = lin & 127;
        dst[(size_t)n * 128 + c] = tl[n][c];
    }
}

// ---- shift MLP layer 0: t0 = w0s @ q  (per point), + channel sum/sumsq
__global__ void k_shift0(const float* __restrict__ xyz, const float* __restrict__ w0s,
                         float* __restrict__ t0, float* __restrict__ stats) {
    __shared__ float ls[64], lq[64];
    int t = threadIdx.x;
    if (t < 64) { ls[t] = 0.f; lq[t] = 0.f; }
    __syncthreads();
    int p = blockIdx.x * 256 + t;
    float q0 = xyz[p*3], q1 = xyz[p*3+1], q2 = xyz[p*3+2];
    for (int o = 0; o < 64; ++o) {
        float v = w0s[o*3]*q0 + w0s[o*3+1]*q1 + w0s[o*3+2]*q2;
        t0[p*64+o] = v;
        atomicAdd(&ls[o], v);
        atomicAdd(&lq[o], v*v);
    }
    __syncthreads();
    if (t < 64) { atomicAdd(&stats[ST_S0S + t], ls[t]); atomicAdd(&stats[ST_S0Q + t], lq[t]); }
}

// ---- shift layer 1: h0 = relu(bn(t0)); t1 = w1s @ h0; + channel sums
__global__ void k_shift1(const float* __restrict__ t0, const float* __restrict__ w1s,
                         const float* __restrict__ g0, const float* __restrict__ b0,
                         float* __restrict__ t1, float* __restrict__ stats) {
    __shared__ float aa[64], bb[64], ls[3], lq[3];
    int t = threadIdx.x;
    if (t < 64) {
        float mean = stats[ST_S0S + t] * (1.f / NQ);
        float var  = stats[ST_S0Q + t] * (1.f / NQ) - mean * mean;
        float a = g0[t] * rsqrtf(var + EPS_);
        aa[t] = a; bb[t] = b0[t] - mean * a;
    }
    if (t < 3) { ls[t] = 0.f; lq[t] = 0.f; }
    __syncthreads();
    int p = blockIdx.x * 256 + t;
    float h[64];
    for (int c = 0; c < 64; ++c) h[c] = fmaxf(0.f, aa[c] * t0[p*64+c] + bb[c]);
    for (int o = 0; o < 3; ++o) {
        float v = 0.f;
        for (int c = 0; c < 64; ++c) v += w1s[o*64+c] * h[c];
        t1[p*3+o] = v;
        atomicAdd(&ls[o], v);
        atomicAdd(&lq[o], v*v);
    }
    __syncthreads();
    if (t < 3) { atomicAdd(&stats[ST_S1S + t], ls[t]); atomicAdd(&stats[ST_S1Q + t], lq[t]); }
}

// ---- shift output: new_xyz = relu(bn(t1))
__global__ void k_shift2(const float* __restrict__ t1, const float* __restrict__ g1,
                         const float* __restrict__ b1, const float* __restrict__ stats,
                         float* __restrict__ nxyz) {
    int p = blockIdx.x * 256 + threadIdx.x;
    for (int o = 0; o < 3; ++o) {
        float mean = stats[ST_S1S + o] * (1.f / NQ);
        float var  = stats[ST_S1Q + o] * (1.f / NQ) - mean * mean;
        float a = g1[o] * rsqrtf(var + EPS_);
        float bbv = b1[o] - mean * a;
        nxyz[p*3+o] = fmaxf(0.f, a * t1[p*3+o] + bbv);
    }
}

// ---- ball query, wave-parallel: one wave (64 lanes) per query.
// Ordered first-32-in-radius preserved via ballot + prefix popcount.
__global__ void k_ballq(const float* __restrict__ bxyz, const float* __restrict__ nxyz,
                        int* __restrict__ idxb) {
    int wq   = blockIdx.x * 4 + (threadIdx.x >> 6);   // query id (4 waves/block)
    int lane = threadIdx.x & 63;
    int b    = wq >> 11;                               // wq / M_
    float qx = nxyz[wq*3], qy = nxyz[wq*3+1], qz = nxyz[wq*3+2];
    float sq = __fadd_rn(__fadd_rn(__fmul_rn(qx,qx), __fmul_rn(qy,qy)), __fmul_rn(qz,qz));
    const float* bp = bxyz + (size_t)b * N_ * 3;
    int* op = idxb + (size_t)wq * 32;
    unsigned long long below = (lane == 63) ? ~0ull >> 1 : ((1ull << lane) - 1ull);
    int cnt = 0, first = 0;
    for (int j0 = 0; j0 < N_ && cnt < 32; j0 += 64) {
        int j = j0 + lane;
        float x = bp[j*3], y = bp[j*3+1], z = bp[j*3+2];
        float sx  = __fadd_rn(__fadd_rn(__fmul_rn(x,x), __fmul_rn(y,y)), __fmul_rn(z,z));
        float dot = __fadd_rn(__fadd_rn(__fmul_rn(qx,x), __fmul_rn(qy,y)), __fmul_rn(qz,z));
        float d2  = __fsub_rn(__fadd_rn(sq, sx), __fmul_rn(2.0f, dot));
        unsigned long long m = __ballot(d2 < R2_);
        if (cnt == 0 && m != 0ull) first = j0 + __ffsll((long long)m) - 1;
        int pre = cnt + __popcll(m & below);
        if (((m >> lane) & 1ull) && pre < 32) op[pre] = j;
        cnt += __popcll(m);
    }
    if (cnt < 32) {
        if (cnt == 0) first = 0;
        for (int k = cnt + lane; k < 32; k += 64) op[k] = first;
    }
}

// ---- GEMM1: gather g (160ch padded) per query, y1 = w0p @ g (bf16 MFMA), store y1 bf16, fused stats
__global__ void __launch_bounds__(256)
k_gemm1(const unsigned short* __restrict__ featT, const float* __restrict__ bxyz,
        const float* __restrict__ nxyz, const int* __restrict__ idxb,
        const unsigned short* __restrict__ w0p, unsigned short* __restrict__ y1,
        float* __restrict__ stats) {
    __shared__ unsigned short gt[32][168];   // [sample][channel], stride 168 -> <=2-way conflicts
    __shared__ int pidx[32];
    int tid  = threadIdx.x;
    int wave = tid >> 6, lane = tid & 63, quad = lane >> 4, l16 = lane & 15;

    s8v afr[2][5];                            // A fragments: rows wave*32 + t2*16 + l16
    for (int t2 = 0; t2 < 2; ++t2)
        for (int kk = 0; kk < 5; ++kk) {
            int row = wave*32 + t2*16 + l16;
            afr[t2][kk] = *(const s8v*)(w0p + row*160 + kk*32 + quad*8);
        }
    f32x4 ssum[2] = {}; f32x4 ssq[2] = {};

    for (int qi = 0; qi < 8; ++qi) {
        int gq = blockIdx.x * 8 + qi;
        int b  = gq >> 11;
        if (tid < 32) pidx[tid] = idxb[gq*32 + tid];
        __syncthreads();
        // stage features: 8 threads per sample, 16 ch each (two 16B loads)
        {
            int s = tid >> 3, part = tid & 7;
            int pp = pidx[s];
            const unsigned short* src = featT + ((size_t)(b * N_ + pp)) * 128 + part * 16;
            s8v v0 = *(const s8v*)src;
            s8v v1 = *(const s8v*)(src + 8);
            *(s8v*)&gt[s][part*16]     = v0;
            *(s8v*)&gt[s][part*16 + 8] = v1;
        }
        if (tid < 32) {   // rel xyz at ch 128..130, zeros 131..159
            int pp = pidx[tid];
            const float* bx = bxyz + (size_t)(b * N_ + pp) * 3;
            float rx = bx[0] - nxyz[gq*3];
            float ry = bx[1] - nxyz[gq*3+1];
            float rz = bx[2] - nxyz[gq*3+2];
            gt[tid][128] = f2bf(rx); gt[tid][129] = f2bf(ry); gt[tid][130] = f2bf(rz);
            for (int c = 131; c < 160; ++c) gt[tid][c] = 0;
        }
        __syncthreads();
        f32x4 acc[2][2] = {};
        for (int kk = 0; kk < 5; ++kk) {
            s8v bf0 = *(const s8v*)&gt[l16][kk*32 + quad*8];
            s8v bf1 = *(const s8v*)&gt[l16 + 16][kk*32 + quad*8];
            for (int t2 = 0; t2 < 2; ++t2) {
                acc[t2][0] = __builtin_amdgcn_mfma_f32_16x16x32_bf16(afr[t2][kk], bf0, acc[t2][0], 0, 0, 0);
                acc[t2][1] = __builtin_amdgcn_mfma_f32_16x16x32_bf16(afr[t2][kk], bf1, acc[t2][1], 0, 0, 0);
            }
        }
        for (int t2 = 0; t2 < 2; ++t2)
            for (int n = 0; n < 2; ++n) {
                int sg  = gq*32 + n*16 + l16;
                int ch0 = wave*32 + t2*16 + quad*4;
                f32x4 a = acc[t2][n];
                s4v pk;
                pk.x = (short)f2bf(a.x); pk.y = (short)f2bf(a.y);
                pk.z = (short)f2bf(a.z); pk.w = (short)f2bf(a.w);
                *(s4v*)(y1 + (size_t)sg * 128 + ch0) = pk;
                ssum[t2] += a;
                ssq[t2]  += a * a;
            }
        __syncthreads();
    }
    for (int t2 = 0; t2 < 2; ++t2)
        for (int r = 0; r < 4; ++r) {
            float s = ssum[t2][r], q = ssq[t2][r];
            for (int mk = 1; mk < 16; mk <<= 1) { s += __shfl_xor(s, mk); q += __shfl_xor(q, mk); }
            if (l16 == 0) {
                int ch = wave*32 + t2*16 + quad*4 + r;
                atomicAdd(&stats[ST_M1S + ch], s);
                atomicAdd(&stats[ST_M1Q + ch], q);
            }
        }
}

// ---- GEMM2: h1 = relu(bn1(y1)) staged bf16; y2 = w1p @ h1.
// FINAL=false: accumulate bn2 stats only.  FINAL=true: bn2+relu+max-over-32 -> out.
template <bool FINAL>
__global__ void __launch_bounds__(256)
k_gemm2(const unsigned short* __restrict__ y1, const unsigned short* __restrict__ w1p,
        const float* __restrict__ g1m, const float* __restrict__ b1m,
        const float* __restrict__ g2m, const float* __restrict__ b2m,
        float* __restrict__ stats, float* __restrict__ out) {
    __shared__ unsigned short ht[32][136];    // stride 136 -> <=2-way conflicts
    __shared__ float a1l[128], b1l[128];
    __shared__ float a2l[256], b2l[256];
    int tid = threadIdx.x;
    if (tid < 128) {
        float mean = stats[ST_M1S + tid] * (1.f / SAMP);
        float var  = stats[ST_M1Q + tid] * (1.f / SAMP) - mean * mean;
        float a = g1m[tid] * rsqrtf(var + EPS_);
        a1l[tid] = a; b1l[tid] = b1m[tid] - mean * a;
    }
    if (FINAL) {
        float mean = stats[ST_M2S + tid] * (1.f / SAMP);
        float var  = stats[ST_M2Q + tid] * (1.f / SAMP) - mean * mean;
        float a = g2m[tid] * rsqrtf(var + EPS_);
        a2l[tid] = a; b2l[tid] = b2m[tid] - mean * a;
    }
    __syncthreads();
    int wave = tid >> 6, lane = tid & 63, quad = lane >> 4, l16 = lane & 15;
    s8v afr[4][4];
    for (int t4 = 0; t4 < 4; ++t4)
        for (int kk = 0; kk < 4; ++kk) {
            int row = wave*64 + t4*16 + l16;
            afr[t4][kk] = *(const s8v*)(w1p + row*128 + kk*32 + quad*8);
        }
    f32x4 ssum[4] = {}; f32x4 ssq[4] = {};
    for (int qi = 0; qi < 8; ++qi) {
        int gq = blockIdx.x * 8 + qi;
        {   // stage h1 = relu(bn1(y1)) as bf16
            int s = tid >> 3, part = tid & 7;
            const unsigned short* src = y1 + ((size_t)(gq*32 + s)) * 128 + part * 16;
            s8v v0 = *(const s8v*)src;
            s8v v1 = *(const s8v*)(src + 8);
            s8v o0, o1;
            for (int e = 0; e < 8; ++e) {
                int c0 = part*16 + e, c1 = c0 + 8;
                float f0 = bf2f((unsigned short)v0[e]);
                float f1 = bf2f((unsigned short)v1[e]);
                o0[e] = (short)f2bf(fmaxf(0.f, a1l[c0]*f0 + b1l[c0]));
                o1[e] = (short)f2bf(fmaxf(0.f, a1l[c1]*f1 + b1l[c1]));
            }
            *(s8v*)&ht[s][part*16]     = o0;
            *(s8v*)&ht[s][part*16 + 8] = o1;
        }
        __syncthreads();
        f32x4 acc[4][2] = {};
        for (int kk = 0; kk < 4; ++kk) {
            s8v bf0 = *(const s8v*)&ht[l16][kk*32 + quad*8];
            s8v bf1 = *(const s8v*)&ht[l16 + 16][kk*32 + quad*8];
            for (int t4 = 0; t4 < 4; ++t4) {
                acc[t4][0] = __builtin_amdgcn_mfma_f32_16x16x32_bf16(afr[t4][kk], bf0, acc[t4][0], 0, 0, 0);
                acc[t4][1] = __builtin_amdgcn_mfma_f32_16x16x32_bf16(afr[t4][kk], bf1, acc[t4][1], 0, 0, 0);
            }
        }
        if (FINAL) {
            for (int t4 = 0; t4 < 4; ++t4) {
                int ch0 = wave*64 + t4*16 + quad*4;
                f32x4 res;
                for (int r = 0; r < 4; ++r) {
                    float a2 = a2l[ch0 + r], bb2 = b2l[ch0 + r];
                    float v0 = fmaxf(0.f, a2 * acc[t4][0][r] + bb2);
                    float v1 = fmaxf(0.f, a2 * acc[t4][1][r] + bb2);
                    float m = fmaxf(v0, v1);
                    for (int mk = 1; mk < 16; mk <<= 1) m = fmaxf(m, __shfl_xor(m, mk));
                    res[r] = m;
                }
                if (l16 == 0) *(f32x4*)(out + (size_t)gq * 256 + ch0) = res;
            }
        } else {
            for (int t4 = 0; t4 < 4; ++t4)
                for (int n = 0; n < 2; ++n) { ssum[t4] += acc[t4][n]; ssq[t4] += acc[t4][n] * acc[t4][n]; }
        }
        __syncthreads();
    }
    if (!FINAL) {
        for (int t4 = 0; t4 < 4; ++t4)
            for (int r = 0; r < 4; ++r) {
                float s = ssum[t4][r], q = ssq[t4][r];
                for (int mk = 1; mk < 16; mk <<= 1) { s += __shfl_xor(s, mk); q += __shfl_xor(q, mk); }
                if (l16 == 0) {
                    int ch = wave*64 + t4*16 + quad*4 + r;
                    atomicAdd(&stats[ST_M2S + ch], s);
                    atomicAdd(&stats[ST_M2Q + ch], q);
                }
            }
    }
}

extern "C" void kernel_launch(void* const* d_in, const int* in_sizes, int n_in,
                              void* d_out, int out_size, void* d_ws, size_t ws_size,
                              hipStream_t stream) {
    const float* ffps = (const float*)d_in[0];
    const float* bxyz = (const float*)d_in[1];
    const float* feat = (const float*)d_in[2];
    const float* sw0  = (const float*)d_in[3];
    const float* sg0  = (const float*)d_in[4];
    const float* sb0  = (const float*)d_in[5];
    const float* sw1  = (const float*)d_in[6];
    const float* sg1  = (const float*)d_in[7];
    const float* sb1  = (const float*)d_in[8];
    const float* mw0  = (const float*)d_in[9];
    const float* mg0  = (const float*)d_in[10];
    const float* mb0  = (const float*)d_in[11];
    const float* mw1  = (const float*)d_in[12];
    const float* mg1  = (const float*)d_in[13];
    const float* mb1  = (const float*)d_in[14];
    float* out = (float*)d_out;

    char* ws = (char*)d_ws;
    size_t off = 0;
    auto alloc = [&](size_t bytes) -> void* {
        void* p = ws + off;
        off += (bytes + 255) & ~(size_t)255;
        return p;
    };
    float*          stats = (float*)alloc(1024 * 4);
    float*          t0    = (float*)alloc((size_t)NQ * 64 * 4);
    float*          t1    = (float*)alloc((size_t)NQ * 3 * 4);
    float*          nxyz  = (float*)alloc((size_t)NQ * 3 * 4);
    int*            idxb  = (int*)alloc((size_t)NQ * 32 * 4);
    unsigned short* w0p   = (unsigned short*)alloc(128 * 160 * 2);
    unsigned short* w1p   = (unsigned short*)alloc(256 * 128 * 2);
    unsigned short* featT = (unsigned short*)alloc((size_t)B_ * N_ * 128 * 2);
    unsigned short* y1    = (unsigned short*)alloc((size_t)SAMP * 128 * 2);
    (void)in_sizes; (void)n_in; (void)out_size; (void)ws_size;

    hipMemsetAsync(stats, 0, 1024 * 4, stream);
    k_prep_w   <<<208, 256, 0, stream>>>(mw0, mw1, w0p, w1p);
    k_transpose<<<B_ * 256, 256, 0, stream>>>(feat, featT);
    k_shift0   <<<NQ / 256, 256, 0, stream>>>(ffps, sw0, t0, stats);
    k_shift1   <<<NQ / 256, 256, 0, stream>>>(t0, sw1, sg0, sb0, t1, stats);
    k_shift2   <<<NQ / 256, 256, 0, stream>>>(t1, sg1, sb1, stats, nxyz);
    k_ballq    <<<NQ / 4, 256, 0, stream>>>(bxyz, nxyz, idxb);
    k_gemm1    <<<NQ / 8, 256, 0, stream>>>(featT, bxyz, nxyz, idxb, w0p, y1, stats);
    k_gemm2<false><<<NQ / 8, 256, 0, stream>>>(y1, w1p, mg0, mb0, mg1, mb1, stats, out);
    k_gemm2<true> <<<NQ / 8, 256, 0, stream>>>(y1, w1p, mg0, mb0, mg1, mb1, stats, out);
}

// Round 3
// 487.954 us; speedup vs baseline: 4.0735x; 1.4768x over previous
//
#include <hip/hip_runtime.h>
#include <cstddef>
#include <cstdint>

#define B_ 4
#define N_ 16384
#define M_ 2048
#define C_ 128
#define NQ (B_*M_)         // 8192 queries
#define NSAMP 32
#define SAMP (NQ*NSAMP)    // 262144 samples
#define EPS_ 1e-5f
#define R2_ 9.0f

typedef short s8v  __attribute__((ext_vector_type(8)));
typedef short s4v  __attribute__((ext_vector_type(4)));
typedef float f32x4 __attribute__((ext_vector_type(4)));

#define ST_S0S 0
#define ST_S0Q 64
#define ST_S1S 128
#define ST_S1Q 136
#define ST_M1S 144
#define ST_M1Q 272
#define ST_M2S 400
#define ST_M2Q 656

__device__ __forceinline__ unsigned short f2bf(float f) {
    unsigned int u = __builtin_bit_cast(unsigned int, f);
    u += 0x7fffu + ((u >> 16) & 1u);     // round-to-nearest-even
    return (unsigned short)(u >> 16);
}
__device__ __forceinline__ float bf2f(unsigned short h) {
    unsigned int u = ((unsigned int)h) << 16;
    return __builtin_bit_cast(float, u);
}

// ---- prep: reorder+pad mlp_w0 (128x131 -> 128x160 bf16, feat-first), cast mlp_w1 (256x128 bf16)
__global__ void k_prep_w(const float* __restrict__ w0, const float* __restrict__ w1,
                         unsigned short* __restrict__ w0p, unsigned short* __restrict__ w1p) {
    int i = blockIdx.x * 256 + threadIdx.x;
    const int tot0 = 128 * 160;
    if (i < tot0) {
        int o = i / 160, c = i - o * 160;
        float v = 0.f;
        if (c < 128)      v = w0[o * 131 + 3 + c];
        else if (c < 131) v = w0[o * 131 + (c - 128)];
        w0p[i] = f2bf(v);
    }
    int j = i - tot0;
    if (j >= 0 && j < 256 * 128) w1p[j] = f2bf(w1[j]);
}

// ---- transpose backbone_features (B,C,N) f32 -> featT (B,N,C) bf16
__global__ void k_transpose(const float* __restrict__ feat, unsigned short* __restrict__ featT) {
    __shared__ unsigned short tl[64][130];
    int b  = blockIdx.x >> 8;
    int n0 = (blockIdx.x & 255) * 64;
    const float* src = feat + (size_t)b * C_ * N_;
    int t = threadIdx.x;
    for (int i = 0; i < 32; ++i) {
        int lin = i * 256 + t;
        int c = lin >> 6, n = lin & 63;
        tl[n][c] = f2bf(src[(size_t)c * N_ + n0 + n]);
    }
    __syncthreads();
    unsigned short* dst = featT + ((size_t)b * N_ + n0) * 128;
    for (int i = 0; i < 32; ++i) {
        int lin = i * 256 + t;
        int n = lin >> 7, c = lin & 127;
        dst[(size_t)n * 128 + c] = tl[n][c];
    }
}

// ---- shift MLP layer 0: t0 = w0s @ q; stats via wave shuffle-reduce (no LDS atomics)
__global__ void k_shift0(const float* __restrict__ xyz, const float* __restrict__ w0s,
                         float* __restrict__ t0, float* __restrict__ stats) {
    __shared__ float w[192];
    __shared__ float ps[4][64], pq[4][64];
    int t = threadIdx.x, wave = t >> 6, lane = t & 63;
    if (t < 192) w[t] = w0s[t];
    __syncthreads();
    int p = blockIdx.x * 256 + t;
    float q0 = xyz[p*3], q1 = xyz[p*3+1], q2 = xyz[p*3+2];
    float* orow = t0 + (size_t)p * 64;
    #pragma unroll
    for (int o = 0; o < 64; ++o) {
        float v = w[3*o]*q0 + w[3*o+1]*q1 + w[3*o+2]*q2;
        orow[o] = v;
        float s = v, sq = v * v;
        #pragma unroll
        for (int mk = 32; mk; mk >>= 1) { s += __shfl_xor(s, mk); sq += __shfl_xor(sq, mk); }
        if (lane == 0) { ps[wave][o] = s; pq[wave][o] = sq; }
    }
    __syncthreads();
    if (t < 64) {
        float s = ps[0][t] + ps[1][t] + ps[2][t] + ps[3][t];
        float q = pq[0][t] + pq[1][t] + pq[2][t] + pq[3][t];
        atomicAdd(&stats[ST_S0S + t], s);
        atomicAdd(&stats[ST_S0Q + t], q);
    }
}

// ---- shift layer 1: h0 = relu(bn(t0)); t1 = w1s @ h0; stats via shuffle-reduce
__global__ void k_shift1(const float* __restrict__ t0, const float* __restrict__ w1s,
                         const float* __restrict__ g0, const float* __restrict__ b0,
                         float* __restrict__ t1, float* __restrict__ stats) {
    __shared__ float aa[64], bb[64], wl[192];
    __shared__ float ps[4][3], pq[4][3];
    int t = threadIdx.x, wave = t >> 6, lane = t & 63;
    if (t < 64) {
        float mean = stats[ST_S0S + t] * (1.f / NQ);
        float var  = stats[ST_S0Q + t] * (1.f / NQ) - mean * mean;
        float a = g0[t] * rsqrtf(var + EPS_);
        aa[t] = a; bb[t] = b0[t] - mean * a;
    }
    if (t < 192) wl[t] = w1s[t];
    __syncthreads();
    int p = blockIdx.x * 256 + t;
    const f32x4* xr = (const f32x4*)(t0 + (size_t)p * 64);
    float v0 = 0.f, v1 = 0.f, v2 = 0.f;
    #pragma unroll
    for (int i = 0; i < 16; ++i) {
        f32x4 x = xr[i];
        #pragma unroll
        for (int j = 0; j < 4; ++j) {
            int c = 4*i + j;
            float h = fmaxf(0.f, aa[c] * x[j] + bb[c]);
            v0 += wl[c] * h; v1 += wl[64 + c] * h; v2 += wl[128 + c] * h;
        }
    }
    t1[p*3] = v0; t1[p*3+1] = v1; t1[p*3+2] = v2;
    float vv[3] = {v0, v1, v2};
    #pragma unroll
    for (int o = 0; o < 3; ++o) {
        float s = vv[o], q = vv[o] * vv[o];
        #pragma unroll
        for (int mk = 32; mk; mk >>= 1) { s += __shfl_xor(s, mk); q += __shfl_xor(q, mk); }
        if (lane == 0) { ps[wave][o] = s; pq[wave][o] = q; }
    }
    __syncthreads();
    if (t < 3) {
        float s = ps[0][t] + ps[1][t] + ps[2][t] + ps[3][t];
        float q = pq[0][t] + pq[1][t] + pq[2][t] + pq[3][t];
        atomicAdd(&stats[ST_S1S + t], s);
        atomicAdd(&stats[ST_S1Q + t], q);
    }
}

// ---- shift output: new_xyz = relu(bn(t1))
__global__ void k_shift2(const float* __restrict__ t1, const float* __restrict__ g1,
                         const float* __restrict__ b1, const float* __restrict__ stats,
                         float* __restrict__ nxyz) {
    int p = blockIdx.x * 256 + threadIdx.x;
    for (int o = 0; o < 3; ++o) {
        float mean = stats[ST_S1S + o] * (1.f / NQ);
        float var  = stats[ST_S1Q + o] * (1.f / NQ) - mean * mean;
        float a = g1[o] * rsqrtf(var + EPS_);
        float bbv = b1[o] - mean * a;
        nxyz[p*3+o] = fmaxf(0.f, a * t1[p*3+o] + bbv);
    }
}

// ---- ball query, wave-parallel: one wave per query, ballot + prefix popcount
__global__ void k_ballq(const float* __restrict__ bxyz, const float* __restrict__ nxyz,
                        int* __restrict__ idxb) {
    int wq   = blockIdx.x * 4 + (threadIdx.x >> 6);
    int lane = threadIdx.x & 63;
    int b    = wq >> 11;
    float qx = nxyz[wq*3], qy = nxyz[wq*3+1], qz = nxyz[wq*3+2];
    float sq = __fadd_rn(__fadd_rn(__fmul_rn(qx,qx), __fmul_rn(qy,qy)), __fmul_rn(qz,qz));
    const float* bp = bxyz + (size_t)b * N_ * 3;
    int* op = idxb + (size_t)wq * 32;
    unsigned long long below = (lane == 63) ? ~0ull >> 1 : ((1ull << lane) - 1ull);
    int cnt = 0, first = 0;
    for (int j0 = 0; j0 < N_ && cnt < 32; j0 += 64) {
        int j = j0 + lane;
        float x = bp[j*3], y = bp[j*3+1], z = bp[j*3+2];
        float sx  = __fadd_rn(__fadd_rn(__fmul_rn(x,x), __fmul_rn(y,y)), __fmul_rn(z,z));
        float dot = __fadd_rn(__fadd_rn(__fmul_rn(qx,x), __fmul_rn(qy,y)), __fmul_rn(qz,z));
        float d2  = __fsub_rn(__fadd_rn(sq, sx), __fmul_rn(2.0f, dot));
        unsigned long long m = __ballot(d2 < R2_);
        if (cnt == 0 && m != 0ull) first = j0 + __ffsll((long long)m) - 1;
        int pre = cnt + __popcll(m & below);
        if (((m >> lane) & 1ull) && pre < 32) op[pre] = j;
        cnt += __popcll(m);
    }
    if (cnt < 32) {
        if (cnt == 0) first = 0;
        for (int k = cnt + lane; k < 32; k += 64) op[k] = first;
    }
}

// ---- GEMM1: gather g per query, y1 = w0p @ g (bf16 MFMA), fused bn1 stats
__global__ void __launch_bounds__(256)
k_gemm1(const unsigned short* __restrict__ featT, const float* __restrict__ bxyz,
        const float* __restrict__ nxyz, const int* __restrict__ idxb,
        const unsigned short* __restrict__ w0p, unsigned short* __restrict__ y1,
        float* __restrict__ stats) {
    __shared__ unsigned short gt[32][168];
    __shared__ int pidx[8][32];
    __shared__ float nq[8][3];
    int tid  = threadIdx.x;
    int wave = tid >> 6, lane = tid & 63, quad = lane >> 4, l16 = lane & 15;

    s8v afr[2][5];
    #pragma unroll
    for (int t2 = 0; t2 < 2; ++t2)
        #pragma unroll
        for (int kk = 0; kk < 5; ++kk) {
            int row = wave*32 + t2*16 + l16;
            afr[t2][kk] = *(const s8v*)(w0p + row*160 + kk*32 + quad*8);
        }
    // preload indices + query centers for all 8 queries; zero pad region once
    pidx[tid >> 5][tid & 31] = idxb[blockIdx.x * 256 + tid];
    if (tid < 24) nq[tid / 3][tid % 3] = nxyz[blockIdx.x * 24 + tid];
    {   // zero gt[s][131..159] once (rewritten identically each query)
        int s = tid >> 3, c0 = 131 + (tid & 7) * 4;
        if (c0 < 160) {
            gt[s][c0] = 0;
            if (c0 + 1 < 160) gt[s][c0+1] = 0;
            if (c0 + 2 < 160) gt[s][c0+2] = 0;
            if (c0 + 3 < 160) gt[s][c0+3] = 0;
        }
        gt[s][131] = 0;  // ensure 131 covered
    }
    f32x4 ssum[2] = {}; f32x4 ssq[2] = {};
    int b = blockIdx.x >> 8;    // 256 queries/block group -> batch = blockIdx/256

    for (int qi = 0; qi < 8; ++qi) {
        int gq = blockIdx.x * 8 + qi;
        __syncthreads();
        {   // stage features: 8 threads per sample, 16 ch each
            int s = tid >> 3, part = tid & 7;
            int pp = pidx[qi][s];
            const unsigned short* src = featT + ((size_t)(b * N_ + pp)) * 128 + part * 16;
            s8v v0 = *(const s8v*)src;
            s8v v1 = *(const s8v*)(src + 8);
            *(s8v*)&gt[s][part*16]     = v0;
            *(s8v*)&gt[s][part*16 + 8] = v1;
        }
        if (tid < 32) {   // rel xyz at ch 128..130
            int pp = pidx[qi][tid];
            const float* bx = bxyz + (size_t)(b * N_ + pp) * 3;
            gt[tid][128] = f2bf(bx[0] - nq[qi][0]);
            gt[tid][129] = f2bf(bx[1] - nq[qi][1]);
            gt[tid][130] = f2bf(bx[2] - nq[qi][2]);
        }
        __syncthreads();
        f32x4 acc[2][2] = {};
        #pragma unroll
        for (int kk = 0; kk < 5; ++kk) {
            s8v bf0 = *(const s8v*)&gt[l16][kk*32 + quad*8];
            s8v bf1 = *(const s8v*)&gt[l16 + 16][kk*32 + quad*8];
            #pragma unroll
            for (int t2 = 0; t2 < 2; ++t2) {
                acc[t2][0] = __builtin_amdgcn_mfma_f32_16x16x32_bf16(afr[t2][kk], bf0, acc[t2][0], 0, 0, 0);
                acc[t2][1] = __builtin_amdgcn_mfma_f32_16x16x32_bf16(afr[t2][kk], bf1, acc[t2][1], 0, 0, 0);
            }
        }
        #pragma unroll
        for (int t2 = 0; t2 < 2; ++t2)
            #pragma unroll
            for (int n = 0; n < 2; ++n) {
                int sg  = gq*32 + n*16 + l16;
                int ch0 = wave*32 + t2*16 + quad*4;
                f32x4 a = acc[t2][n];
                s4v pk;
                pk.x = (short)f2bf(a.x); pk.y = (short)f2bf(a.y);
                pk.z = (short)f2bf(a.z); pk.w = (short)f2bf(a.w);
                *(s4v*)(y1 + (size_t)sg * 128 + ch0) = pk;
                ssum[t2] += a;
                ssq[t2]  += a * a;
            }
    }
    #pragma unroll
    for (int t2 = 0; t2 < 2; ++t2)
        #pragma unroll
        for (int r = 0; r < 4; ++r) {
            float s = ssum[t2][r], q = ssq[t2][r];
            for (int mk = 1; mk < 16; mk <<= 1) { s += __shfl_xor(s, mk); q += __shfl_xor(q, mk); }
            if (l16 == 0) {
                int ch = wave*32 + t2*16 + quad*4 + r;
                atomicAdd(&stats[ST_M1S + ch], s);
                atomicAdd(&stats[ST_M1Q + ch], q);
            }
        }
}

// ---- GEMM2: h1 = relu(bn1(y1)) staged bf16 (bn coeffs in REGISTERS); y2 = w1p @ h1.
template <bool FINAL>
__global__ void __launch_bounds__(256)
k_gemm2(const unsigned short* __restrict__ y1, const unsigned short* __restrict__ w1p,
        const float* __restrict__ g1m, const float* __restrict__ b1m,
        const float* __restrict__ g2m, const float* __restrict__ b2m,
        float* __restrict__ stats, float* __restrict__ out) {
    __shared__ unsigned short ht[32][136];
    __shared__ float a1l[128], b1l[128];
    __shared__ float a2l[256], b2l[256];
    int tid = threadIdx.x;
    if (tid < 128) {
        float mean = stats[ST_M1S + tid] * (1.f / SAMP);
        float var  = stats[ST_M1Q + tid] * (1.f / SAMP) - mean * mean;
        float a = g1m[tid] * rsqrtf(var + EPS_);
        a1l[tid] = a; b1l[tid] = b1m[tid] - mean * a;
    }
    if (FINAL) {
        float mean = stats[ST_M2S + tid] * (1.f / SAMP);
        float var  = stats[ST_M2Q + tid] * (1.f / SAMP) - mean * mean;
        float a = g2m[tid] * rsqrtf(var + EPS_);
        a2l[tid] = a; b2l[tid] = b2m[tid] - mean * a;
    }
    __syncthreads();
    int wave = tid >> 6, lane = tid & 63, quad = lane >> 4, l16 = lane & 15;
    int s = tid >> 3, part = tid & 7;

    // hoist per-thread bn1 coefficients (channels part*16 .. part*16+15) into registers
    float a1r[16], b1r[16];
    {
        const float* ap = &a1l[part * 16];
        const float* bp = &b1l[part * 16];
        #pragma unroll
        for (int i = 0; i < 16; ++i) { a1r[i] = ap[i]; b1r[i] = bp[i]; }
    }
    // hoist FINAL bn2 coefficients (per-lane output channels) into registers
    float a2r[16], b2r[16];
    if (FINAL) {
        const float* ap = &a2l[wave*64 + quad*4];
        const float* bp = &b2l[wave*64 + quad*4];
        #pragma unroll
        for (int t4 = 0; t4 < 4; ++t4)
            #pragma unroll
            for (int r = 0; r < 4; ++r) { a2r[t4*4+r] = ap[t4*16+r]; b2r[t4*4+r] = bp[t4*16+r]; }
    }

    s8v afr[4][4];
    #pragma unroll
    for (int t4 = 0; t4 < 4; ++t4)
        #pragma unroll
        for (int kk = 0; kk < 4; ++kk) {
            int row = wave*64 + t4*16 + l16;
            afr[t4][kk] = *(const s8v*)(w1p + row*128 + kk*32 + quad*8);
        }
    f32x4 ssum[4] = {}; f32x4 ssq[4] = {};
    for (int qi = 0; qi < 8; ++qi) {
        int gq = blockIdx.x * 8 + qi;
        {   // stage h1 = relu(bn1(y1)) as bf16, register bn coeffs
            const unsigned short* src = y1 + ((size_t)(gq*32 + s)) * 128 + part * 16;
            s8v v0 = *(const s8v*)src;
            s8v v1 = *(const s8v*)(src + 8);
            s8v o0, o1;
            #pragma unroll
            for (int e = 0; e < 8; ++e) {
                float f0 = bf2f((unsigned short)v0[e]);
                float f1 = bf2f((unsigned short)v1[e]);
                o0[e] = (short)f2bf(fmaxf(0.f, a1r[e]     * f0 + b1r[e]));
                o1[e] = (short)f2bf(fmaxf(0.f, a1r[8 + e] * f1 + b1r[8 + e]));
            }
            *(s8v*)&ht[s][part*16]     = o0;
            *(s8v*)&ht[s][part*16 + 8] = o1;
        }
        __syncthreads();
        f32x4 acc[4][2] = {};
        #pragma unroll
        for (int kk = 0; kk < 4; ++kk) {
            s8v bf0 = *(const s8v*)&ht[l16][kk*32 + quad*8];
            s8v bf1 = *(const s8v*)&ht[l16 + 16][kk*32 + quad*8];
            #pragma unroll
            for (int t4 = 0; t4 < 4; ++t4) {
                acc[t4][0] = __builtin_amdgcn_mfma_f32_16x16x32_bf16(afr[t4][kk], bf0, acc[t4][0], 0, 0, 0);
                acc[t4][1] = __builtin_amdgcn_mfma_f32_16x16x32_bf16(afr[t4][kk], bf1, acc[t4][1], 0, 0, 0);
            }
        }
        if (FINAL) {
            #pragma unroll
            for (int t4 = 0; t4 < 4; ++t4) {
                int ch0 = wave*64 + t4*16 + quad*4;
                f32x4 res;
                #pragma unroll
                for (int r = 0; r < 4; ++r) {
                    float a2 = a2r[t4*4+r], bb2 = b2r[t4*4+r];
                    float v0 = fmaxf(0.f, a2 * acc[t4][0][r] + bb2);
                    float v1 = fmaxf(0.f, a2 * acc[t4][1][r] + bb2);
                    float m = fmaxf(v0, v1);
                    for (int mk = 1; mk < 16; mk <<= 1) m = fmaxf(m, __shfl_xor(m, mk));
                    res[r] = m;
                }
                if (l16 == 0) *(f32x4*)(out + (size_t)gq * 256 + ch0) = res;
            }
        } else {
            #pragma unroll
            for (int t4 = 0; t4 < 4; ++t4)
                #pragma unroll
                for (int n = 0; n < 2; ++n) { ssum[t4] += acc[t4][n]; ssq[t4] += acc[t4][n] * acc[t4][n]; }
        }
        __syncthreads();
    }
    if (!FINAL) {
        #pragma unroll
        for (int t4 = 0; t4 < 4; ++t4)
            #pragma unroll
            for (int r = 0; r < 4; ++r) {
                float sv = ssum[t4][r], q = ssq[t4][r];
                for (int mk = 1; mk < 16; mk <<= 1) { sv += __shfl_xor(sv, mk); q += __shfl_xor(q, mk); }
                if (l16 == 0) {
                    int ch = wave*64 + t4*16 + quad*4 + r;
                    atomicAdd(&stats[ST_M2S + ch], sv);
                    atomicAdd(&stats[ST_M2Q + ch], q);
                }
            }
    }
}

extern "C" void kernel_launch(void* const* d_in, const int* in_sizes, int n_in,
                              void* d_out, int out_size, void* d_ws, size_t ws_size,
                              hipStream_t stream) {
    const float* ffps = (const float*)d_in[0];
    const float* bxyz = (const float*)d_in[1];
    const float* feat = (const float*)d_in[2];
    const float* sw0  = (const float*)d_in[3];
    const float* sg0  = (const float*)d_in[4];
    const float* sb0  = (const float*)d_in[5];
    const float* sw1  = (const float*)d_in[6];
    const float* sg1  = (const float*)d_in[7];
    const float* sb1  = (const float*)d_in[8];
    const float* mw0  = (const float*)d_in[9];
    const float* mg0  = (const float*)d_in[10];
    const float* mb0  = (const float*)d_in[11];
    const float* mw1  = (const float*)d_in[12];
    const float* mg1  = (const float*)d_in[13];
    const float* mb1  = (const float*)d_in[14];
    float* out = (float*)d_out;

    char* ws = (char*)d_ws;
    size_t off = 0;
    auto alloc = [&](size_t bytes) -> void* {
        void* p = ws + off;
        off += (bytes + 255) & ~(size_t)255;
        return p;
    };
    float*          stats = (float*)alloc(1024 * 4);
    float*          t0    = (float*)alloc((size_t)NQ * 64 * 4);
    float*          t1    = (float*)alloc((size_t)NQ * 3 * 4);
    float*          nxyz  = (float*)alloc((size_t)NQ * 3 * 4);
    int*            idxb  = (int*)alloc((size_t)NQ * 32 * 4);
    unsigned short* w0p   = (unsigned short*)alloc(128 * 160 * 2);
    unsigned short* w1p   = (unsigned short*)alloc(256 * 128 * 2);
    unsigned short* featT = (unsigned short*)alloc((size_t)B_ * N_ * 128 * 2);
    unsigned short* y1    = (unsigned short*)alloc((size_t)SAMP * 128 * 2);
    (void)in_sizes; (void)n_in; (void)out_size; (void)ws_size;

    hipMemsetAsync(stats, 0, 1024 * 4, stream);
    k_prep_w   <<<208, 256, 0, stream>>>(mw0, mw1, w0p, w1p);
    k_transpose<<<B_ * 256, 256, 0, stream>>>(feat, featT);
    k_shift0   <<<NQ / 256, 256, 0, stream>>>(ffps, sw0, t0, stats);
    k_shift1   <<<NQ / 256, 256, 0, stream>>>(t0, sw1, sg0, sb0, t1, stats);
    k_shift2   <<<NQ / 256, 256, 0, stream>>>(t1, sg1, sb1, stats, nxyz);
    k_ballq    <<<NQ / 4, 256, 0, stream>>>(bxyz, nxyz, idxb);
    k_gemm1    <<<NQ / 8, 256, 0, stream>>>(featT, bxyz, nxyz, idxb, w0p, y1, stats);
    k_gemm2<false><<<NQ / 8, 256, 0, stream>>>(y1, w1p, mg0, mb0, mg1, mb1, stats, out);
    k_gemm2<true> <<<NQ / 8, 256, 0, stream>>>(y1, w1p, mg0, mb0, mg1, mb1, stats, out);
}